// Round 3
// baseline (376.993 us; speedup 1.0000x reference)
//
#include <hip/hip_runtime.h>
#include <hip/hip_bf16.h>

// Problem: out[s,:] = sum_{i in segment s} (input[i,:] @ W^T + b)
// N = 500000, S = 10000, D_IN = D_OUT = 128.
// Algebraic transform (linear ops commute):
//   out[s] = (sum_{i in seg s} X[i]) @ W^T + count_s * b
// Phase 0: zero Xs scratch (5.12 MB).
// Phase 1: CHUNKED segment row-sum: each block streams a fixed 256-row
//          window (128 KB contiguous), walks the segment pieces inside it,
//          flushes interior segments with plain stores and boundary pieces
//          with f32 atomics. Uniform work per block -> no stragglers.
// Phase 2: small GEMM (10000 x 128 x 128) + count*b epilogue.

#define D 128          // D_IN == D_OUT
#define D4 32          // D/4
#define CHUNK 256      // rows per phase-1 block

__device__ __forceinline__ void f4add(float4& a, const float4& v) {
  a.x += v.x; a.y += v.y; a.z += v.z; a.w += v.w;
}

// ---------------- Phase 0: zero the Xs scratch ----------------
__global__ __launch_bounds__(256) void zero_xs_kernel(float4* Xs4, int n4) {
  int i = blockIdx.x * 256 + threadIdx.x;
  if (i < n4) Xs4[i] = make_float4(0.f, 0.f, 0.f, 0.f);
}

// ---------------- Phase 1: chunked segment row sum ----------------
// 256 threads = 4 waves. rg = tid/32 (0..7) row-group, c4 = tid%32 float4
// column. Wave w covers row-groups {2w, 2w+1}; a shfl_xor(32) folds the
// pair, then 3 waves spill 512B to LDS and wave 0 finishes + flushes.
__global__ __launch_bounds__(256) void seg_sum_chunk_kernel(
    const float* __restrict__ in, const int* __restrict__ graph,
    float* __restrict__ Xs, int N, int S) {
  int tid = threadIdx.x;
  int c4  = tid & 31;
  int rg  = tid >> 5;

  int row0   = blockIdx.x * CHUNK;
  int rowEnd = min(row0 + CHUNK, N) - 1;   // inclusive
  if (row0 > rowEnd) return;               // uniform

  // binary search: largest s with graph[2s] <= row0 (starts are sorted)
  int lo = 0, hi = S - 1;
  while (lo < hi) {
    int mid = (lo + hi + 1) >> 1;
    if (graph[2 * mid] <= row0) lo = mid; else hi = mid - 1;
  }

  __shared__ float4 buf[2][3][32];   // double-buffered -> 1 barrier/piece
  const float4* in4 = (const float4*)in;
  int parity = 0;

  int s = lo;
  while (true) {
    int rs    = graph[2 * s];
    int reRaw = graph[2 * s + 1];
    int nxt   = (s + 1 < S) ? graph[2 * s + 2] : N;  // next segment start
    int re    = min(reRaw, min(nxt - 1, N - 1));     // reference valid-mask
    int rs_c  = max(rs, 0);
    int a     = max(rs_c, row0);
    int b2    = min(re, rowEnd);

    if (a <= b2) {                       // uniform condition
      int len = b2 - a + 1;
      const float4* p = in4 + (size_t)a * D4 + c4;
      float4 acc0 = make_float4(0.f, 0.f, 0.f, 0.f);
      float4 acc1 = make_float4(0.f, 0.f, 0.f, 0.f);
      int r = rg;
      for (; r + 8 < len; r += 16) {     // 2 independent loads in flight
        float4 v0 = p[(size_t)r * D4];
        float4 v1 = p[(size_t)(r + 8) * D4];
        f4add(acc0, v0);
        f4add(acc1, v1);
      }
      for (; r < len; r += 8) f4add(acc0, p[(size_t)r * D4]);
      f4add(acc0, acc1);

      // fold row-group pair within the wave (lane ^ 32)
      float4 o;
      o.x = __shfl_xor(acc0.x, 32, 64);
      o.y = __shfl_xor(acc0.y, 32, 64);
      o.z = __shfl_xor(acc0.z, 32, 64);
      o.w = __shfl_xor(acc0.w, 32, 64);
      f4add(acc0, o);

      int wv = tid >> 6;                 // wave id 0..3
      if ((tid & 32) == 0 && wv > 0) buf[parity][wv - 1][c4] = acc0;
      __syncthreads();
      if (tid < 32) {
        f4add(acc0, buf[parity][0][c4]);
        f4add(acc0, buf[parity][1][c4]);
        f4add(acc0, buf[parity][2][c4]);
        bool full = (rs_c >= row0) && (re <= rowEnd);
        if (full) {
          ((float4*)Xs)[(size_t)s * D4 + c4] = acc0;   // sole owner
        } else {
          float* q = Xs + (size_t)s * D + c4 * 4;      // boundary piece
          atomicAdd(q + 0, acc0.x);
          atomicAdd(q + 1, acc0.y);
          atomicAdd(q + 2, acc0.z);
          atomicAdd(q + 3, acc0.w);
        }
      }
      parity ^= 1;
    }
    if (s + 1 >= S || graph[2 * s + 2] > rowEnd) break;
    ++s;
  }
}

// ---------------- Phase 2: out = Xs @ W^T + cnt*b ----------------
// Tile: 16 segments x 64 output cols per 256-thread block.
#define SEG_PB 16
#define OUT_PB 64
#define WT_STRIDE 65

__global__ __launch_bounds__(256) void seg_gemm_kernel(
    const float* __restrict__ Xs, const float* __restrict__ W,
    const float* __restrict__ b, const int* __restrict__ graph,
    float* __restrict__ out, int N, int S) {
  __shared__ float Wt[D * WT_STRIDE];             // 33.3 KB
  __shared__ __align__(16) float XsL[SEG_PB * D]; // 8 KB
  __shared__ float cntL[SEG_PB];

  int tid   = threadIdx.x;
  int s0    = blockIdx.x * SEG_PB;
  int oBase = blockIdx.y * OUT_PB;

  #pragma unroll
  for (int rnd = 0; rnd < 8; ++rnd) {
    int linear = rnd * 256 + tid;        // 0..2047
    int op     = linear >> 5;            // 0..63 local out row
    int d4     = (linear & 31) << 2;     // 0,4,...,124
    float4 w = *(const float4*)(W + (oBase + op) * D + d4);
    Wt[(d4 + 0) * WT_STRIDE + op] = w.x;
    Wt[(d4 + 1) * WT_STRIDE + op] = w.y;
    Wt[(d4 + 2) * WT_STRIDE + op] = w.z;
    Wt[(d4 + 3) * WT_STRIDE + op] = w.w;
  }
  {
    const float4* src = (const float4*)(Xs + s0 * D);
    float4* dst = (float4*)XsL;
    dst[tid]       = src[tid];
    dst[tid + 256] = src[tid + 256];
  }
  if (tid < SEG_PB) {
    int s   = s0 + tid;
    int rs  = graph[2 * s];
    int re  = graph[2 * s + 1];
    int nxt = (s + 1 < S) ? (graph[2 * s + 2] - 1) : (N - 1);
    re = min(re, min(nxt, N - 1));
    rs = max(rs, 0);
    cntL[tid] = (float)max(0, re - rs + 1);
  }
  __syncthreads();

  int op = tid & 63;   // local out col; whole wave shares g
  int g  = tid >> 6;   // 0..3 segment phase
  float acc[4] = {0.f, 0.f, 0.f, 0.f};

  const float4* xs4 = (const float4*)XsL;
  #pragma unroll 8
  for (int d4 = 0; d4 < D4; ++d4) {
    float w0 = Wt[(4 * d4 + 0) * WT_STRIDE + op];
    float w1 = Wt[(4 * d4 + 1) * WT_STRIDE + op];
    float w2 = Wt[(4 * d4 + 2) * WT_STRIDE + op];
    float w3 = Wt[(4 * d4 + 3) * WT_STRIDE + op];
    #pragma unroll
    for (int j = 0; j < 4; ++j) {
      float4 x = xs4[(4 * j + g) * D4 + d4];  // LDS broadcast
      acc[j] += x.x * w0 + x.y * w1 + x.z * w2 + x.w * w3;
    }
  }

  float bo = b[oBase + op];
  #pragma unroll
  for (int j = 0; j < 4; ++j) {
    int sl = 4 * j + g;
    out[(s0 + sl) * D + oBase + op] = acc[j] + cntL[sl] * bo;
  }
}

extern "C" void kernel_launch(void* const* d_in, const int* in_sizes, int n_in,
                              void* d_out, int out_size, void* d_ws, size_t ws_size,
                              hipStream_t stream) {
  const float* in    = (const float*)d_in[0];
  const int*   graph = (const int*)d_in[1];
  const float* W     = (const float*)d_in[2];
  const float* b     = (const float*)d_in[3];
  float* out = (float*)d_out;

  const int N = in_sizes[0] / D;     // 500000
  const int S = in_sizes[1] / 2;     // 10000

  float* Xs = (float*)d_ws;          // S*128 floats = 5.12 MB scratch

  int n4 = S * D4;                   // 320000 float4
  zero_xs_kernel<<<(n4 + 255) / 256, 256, 0, stream>>>((float4*)Xs, n4);

  int nBlocks = (N + CHUNK - 1) / CHUNK;   // 1954
  seg_sum_chunk_kernel<<<nBlocks, 256, 0, stream>>>(in, graph, Xs, N, S);

  dim3 grid2(S / SEG_PB, D / OUT_PB);  // 625 x 2
  seg_gemm_kernel<<<grid2, 256, 0, stream>>>(Xs, W, b, graph, out, N, S);
}